// Round 12
// baseline (239.456 us; speedup 1.0000x reference)
//
#include <hip/hip_runtime.h>

// 2-layer GCN: counting sort to fine buckets (in-LDS sort + coalesced segment
// flush) + LDS-local CSR + register aggregation, bf16 feature planes:
//   k_hist/k_scan: per-(fine bucket, scatter block) segment offsets
//   k_scatter: 200 blocks x 1024 thr, EPB=16384; block sorts its edges in a
//              64KB LDS buffer then flushes each bucket segment with
//              contiguous stores (R9/R11: scattered-4B-store transaction rate
//              was the bound; ~10x fewer store transactions)
//   k_degprep: per fine bucket degree -> dinv; ag1 = bf16(emb[x_ids]*dinv)
//   k_fuse1:   per fine bucket LDS CSR rebuild; 2 lanes/node register gather
//              (uint4, 4-wide unrolled for MLP); fused 16->32 GEMV+ReLU
//   k_fuse2 x2 (ONE PLANE each -- R8: merged planes blew the 4MB L2): register
//              gather + fused sorted-batch pooling -> atomicAdd P[256][32]
//   k_final:   out[g] = P[g]@W2 + cnt[g]*b2
//
// Standing lessons: R1/R2 no scattered-4B global stores / no hot global
// atomics; R4 no single-block stages; R6 register accumulation only; R3/R8
// one bf16 plane (3.2MB) per gather pass; R10 no cooperative launch.

constexpr int EPB = 16384;         // edges per hist/scatter block
constexpr int BSH = 8;             // 256 nodes per fine bucket
constexpr int BKTN = 1 << BSH;
constexpr int CAP = 10240;         // LDS edge-list capacity (chunked if over)

__device__ inline unsigned short f2bf(float x) {
  unsigned u = __float_as_uint(x);
  u += 0x7FFF + ((u >> 16) & 1);   // round-to-nearest-even
  return (unsigned short)(u >> 16);
}
__device__ inline float bf2f(unsigned short h) {
  return __uint_as_float((unsigned)h << 16);
}
__device__ inline unsigned pk(float a, float b) {
  return (unsigned)f2bf(a) | ((unsigned)f2bf(b) << 16);
}
__device__ __forceinline__ void add8(float acc[8], uint4 v) {
  acc[0] += bf2f(v.x & 0xFFFF); acc[1] += bf2f(v.x >> 16);
  acc[2] += bf2f(v.y & 0xFFFF); acc[3] += bf2f(v.y >> 16);
  acc[4] += bf2f(v.z & 0xFFFF); acc[5] += bf2f(v.z >> 16);
  acc[6] += bf2f(v.w & 0xFFFF); acc[7] += bf2f(v.w >> 16);
}

// 4-wide unrolled neighbor gather (memory-level parallelism; the degree loop
// is otherwise a serial ~200cyc dependent chain per edge)
__device__ __forceinline__ void gather8(const unsigned short* __restrict__ base,
                                        const int* list, int st, int dg,
                                        float acc[8]) {
  int j = 0;
  for (; j + 4 <= dg; j += 4) {
    int r0 = list[st + j], r1 = list[st + j + 1];
    int r2 = list[st + j + 2], r3 = list[st + j + 3];
    uint4 v0 = *(const uint4*)(base + (size_t)r0 * 16);
    uint4 v1 = *(const uint4*)(base + (size_t)r1 * 16);
    uint4 v2 = *(const uint4*)(base + (size_t)r2 * 16);
    uint4 v3 = *(const uint4*)(base + (size_t)r3 * 16);
    add8(acc, v0); add8(acc, v1); add8(acc, v2); add8(acc, v3);
  }
  for (; j < dg; ++j)
    add8(acc, *(const uint4*)(base + (size_t)list[st + j] * 16));
}

// XCD swizzle: adjacent hist columns handled by same-XCD blocks (blk%8 heur.)
__device__ __forceinline__ int swz(int b, int nblkp) {
  return (b & 7) * (nblkp >> 3) + (b >> 3);
}

// per-block LDS histogram of fine col buckets
__global__ __launch_bounds__(1024) void k_hist(const int* __restrict__ col, int E,
                                               int nbkt, int nblkp,
                                               int* __restrict__ hist) {
  __shared__ int h[512];
  int tid = threadIdx.x;
  int blk = swz(blockIdx.x, nblkp);
  for (int i = tid; i < nbkt; i += 1024) h[i] = 0;
  __syncthreads();
  int e0 = blk * EPB, e1 = min(E, e0 + EPB);
  for (int e = e0 + tid; e < e1; e += 1024) atomicAdd(&h[col[e] >> BSH], 1);
  __syncthreads();
  for (int b = tid; b < nbkt; b += 1024) hist[b * nblkp + blk] = h[b];
}

// multi-block scan, stage 1: block-local exclusive scan + block sums
__global__ __launch_bounds__(1024) void k_scan_a(const int* __restrict__ hist, int tot,
                                                 int* __restrict__ off,
                                                 int* __restrict__ bsums) {
  __shared__ int sd[1024];
  int tid = threadIdx.x;
  int i = blockIdx.x * 1024 + tid;
  int v = (i < tot) ? hist[i] : 0;
  sd[tid] = v;
  __syncthreads();
  for (int o = 1; o < 1024; o <<= 1) {
    int u = (tid >= o) ? sd[tid - o] : 0;
    __syncthreads();
    sd[tid] += u;
    __syncthreads();
  }
  if (i < tot) off[i] = sd[tid] - v;  // block-local exclusive
  if (tid == 1023) bsums[blockIdx.x] = sd[tid];
}

// stage 2: add prefix of block sums (tree-reduced); derive bucket starts
__global__ __launch_bounds__(1024) void k_scan_c(int tot, int nblkp, int nbkt, int E,
                                                 int nscan,
                                                 const int* __restrict__ bsums,
                                                 int* __restrict__ off,
                                                 int* __restrict__ bucket_off) {
  __shared__ int sd[1024];
  int tid = threadIdx.x, b = blockIdx.x;
  sd[tid] = (tid < b && tid < nscan) ? bsums[tid] : 0;
  __syncthreads();
  for (int o = 512; o >= 1; o >>= 1) {
    if (tid < o) sd[tid] += sd[tid + o];
    __syncthreads();
  }
  int sbase = sd[0];
  int i = b * 1024 + tid;
  if (i < tot) {
    int v = off[i] + sbase;
    off[i] = v;
    if (i % nblkp == 0) bucket_off[i / nblkp] = v;
  }
  if (i == 0) bucket_off[nbkt] = E;
}

// scatter: in-LDS counting sort of this block's 16K edges, then flush each
// bucket segment with contiguous lane-consecutive stores
__global__ __launch_bounds__(1024) void k_scatter(const int* __restrict__ row,
                                                  const int* __restrict__ col, int E,
                                                  int nbkt, int nblkp,
                                                  const int* __restrict__ off,
                                                  int* __restrict__ staging) {
  __shared__ int sbuf[EPB];
  __shared__ int cnt[512], sc[512], cur[512];
  int tid = threadIdx.x;
  int lane = tid & 63, wv = tid >> 6;
  int blk = swz(blockIdx.x, nblkp);
  if (tid < 512) cnt[tid] = 0;
  __syncthreads();
  int e0 = blk * EPB, e1 = min(E, e0 + EPB);
  for (int e = e0 + tid; e < e1; e += 1024)
    atomicAdd(&cnt[col[e] >> BSH], 1);
  __syncthreads();
  if (tid < 512) sc[tid] = cnt[tid];
  __syncthreads();
  for (int o = 1; o < 512; o <<= 1) {
    int u = (tid < 512 && tid >= o) ? sc[tid - o] : 0;
    __syncthreads();
    if (tid < 512) sc[tid] += u;
    __syncthreads();
  }
  if (tid < 512) { int st = sc[tid] - cnt[tid]; sc[tid] = st; cur[tid] = st; }
  __syncthreads();
  for (int e = e0 + tid; e < e1; e += 1024) {
    int c = col[e];
    int b = c >> BSH;
    int pos = atomicAdd(&cur[b], 1);
    sbuf[pos] = (row[e] << BSH) | (c & (BKTN - 1));
  }
  __syncthreads();
  for (int b = wv; b < nbkt; b += 16) {
    int lbeg = sc[b], lcnt = cnt[b];
    int g = off[b * nblkp + blk];
    for (int j = lane; j < lcnt; j += 64)
      staging[g + j] = sbuf[lbeg + j];
  }
}

// per fine bucket: degree -> dinv; fused embedding: ag1 = bf16(emb[id]*dinv)
__global__ __launch_bounds__(BKTN) void k_degprep(const int* __restrict__ staging,
                                                  const int* __restrict__ bucket_off,
                                                  const int* __restrict__ x_ids,
                                                  const float* __restrict__ emb,
                                                  int N,
                                                  float* __restrict__ dinv,
                                                  unsigned short* __restrict__ ag1) {
  __shared__ int cnt[BKTN];
  int tid = threadIdx.x, b = blockIdx.x;
  int beg = bucket_off[b], end = bucket_off[b + 1];
  cnt[tid] = 0;
  __syncthreads();
  for (int i = beg + tid; i < end; i += BKTN)
    atomicAdd(&cnt[staging[i] & (BKTN - 1)], 1);
  __syncthreads();
  int node = (b << BSH) + tid;
  if (node >= N) return;
  float d = rsqrtf((float)(cnt[tid] + 1));  // +1 self-loop
  dinv[node] = d;
  const float* er = emb + (size_t)x_ids[node] * 16;
  float4 e0 = *(const float4*)(er);
  float4 e1 = *(const float4*)(er + 4);
  float4 e2 = *(const float4*)(er + 8);
  float4 e3 = *(const float4*)(er + 12);
  uint4 o0, o1;
  o0.x = pk(e0.x * d, e0.y * d); o0.y = pk(e0.z * d, e0.w * d);
  o0.z = pk(e1.x * d, e1.y * d); o0.w = pk(e1.z * d, e1.w * d);
  o1.x = pk(e2.x * d, e2.y * d); o1.y = pk(e2.z * d, e2.w * d);
  o1.z = pk(e3.x * d, e3.y * d); o1.w = pk(e3.z * d, e3.w * d);
  *(uint4*)(ag1 + (size_t)node * 16) = o0;
  *(uint4*)(ag1 + (size_t)node * 16 + 8) = o1;
}

// layer 1: LDS CSR rebuild + register aggregation + fused GEMV/ReLU.
// 512 threads: 2 lanes/node (half = 8 features, uint4 gathers).
__global__ __launch_bounds__(512) void k_fuse1(const unsigned short* __restrict__ ag1,
                                               const int* __restrict__ staging,
                                               const int* __restrict__ bucket_off,
                                               const float* __restrict__ dinv,
                                               const float* __restrict__ W1,
                                               const float* __restrict__ b1, int N,
                                               unsigned short* __restrict__ y1g) {
  __shared__ int list[CAP];
  __shared__ int cnt[BKTN], sc[BKTN], lcur[BKTN];
  __shared__ float W[512];
  __shared__ float bb[32];
  int tid = threadIdx.x, b = blockIdx.x;
  W[tid] = W1[tid];
  if (tid < 32) bb[tid] = b1[tid];
  int nloc = tid >> 1, half = tid & 1;
  int node = (b << BSH) + nloc;
  float acc[8];
  if (node < N) {
    uint4 v = *(const uint4*)(ag1 + (size_t)node * 16 + half * 8);
    acc[0] = bf2f(v.x & 0xFFFF); acc[1] = bf2f(v.x >> 16);
    acc[2] = bf2f(v.y & 0xFFFF); acc[3] = bf2f(v.y >> 16);
    acc[4] = bf2f(v.z & 0xFFFF); acc[5] = bf2f(v.z >> 16);
    acc[6] = bf2f(v.w & 0xFFFF); acc[7] = bf2f(v.w >> 16);
  } else {
#pragma unroll
    for (int k = 0; k < 8; ++k) acc[k] = 0.f;
  }
  int beg = bucket_off[b], end = bucket_off[b + 1];
  for (int cbeg = beg; cbeg < end; cbeg += CAP) {
    int cend = min(end, cbeg + CAP);
    if (tid < BKTN) cnt[tid] = 0;
    __syncthreads();
    for (int i = cbeg + tid; i < cend; i += 512)
      atomicAdd(&cnt[staging[i] & (BKTN - 1)], 1);
    __syncthreads();
    if (tid < BKTN) sc[tid] = cnt[tid];
    __syncthreads();
    for (int o = 1; o < BKTN; o <<= 1) {
      int u = (tid < BKTN && tid >= o) ? sc[tid - o] : 0;
      __syncthreads();
      if (tid < BKTN) sc[tid] += u;
      __syncthreads();
    }
    if (tid < BKTN) {
      int st = sc[tid] - cnt[tid];
      sc[tid] = st;
      lcur[tid] = st;
    }
    __syncthreads();
    for (int i = cbeg + tid; i < cend; i += 512) {
      int p = staging[i];
      int pos = atomicAdd(&lcur[p & (BKTN - 1)], 1);
      list[pos] = p >> BSH;
    }
    __syncthreads();
    if (node < N) gather8(ag1 + half * 8, list, sc[nloc], cnt[nloc], acc);
    __syncthreads();
  }
  if (node >= N) return;
  float d = dinv[node];
  float sx[8], xo[8];
#pragma unroll
  for (int k = 0; k < 8; ++k) sx[k] = acc[k] * d;
#pragma unroll
  for (int k = 0; k < 8; ++k) xo[k] = __shfl_xor(sx[k], 1);
  float x[16];
  if (half == 0) {
#pragma unroll
    for (int k = 0; k < 8; ++k) { x[k] = sx[k]; x[8 + k] = xo[k]; }
  } else {
#pragma unroll
    for (int k = 0; k < 8; ++k) { x[k] = xo[k]; x[8 + k] = sx[k]; }
  }
  int j0 = half * 16;
  float a[16];
#pragma unroll
  for (int j = 0; j < 16; ++j) a[j] = bb[j0 + j];
#pragma unroll
  for (int k = 0; k < 16; ++k) {
    float xv = x[k];
#pragma unroll
    for (int j = 0; j < 16; ++j) a[j] += xv * W[k * 32 + j0 + j];
  }
#pragma unroll
  for (int j = 0; j < 16; ++j) a[j] = fmaxf(a[j], 0.f) * d;
  uint4 o0 = {pk(a[0], a[1]), pk(a[2], a[3]), pk(a[4], a[5]), pk(a[6], a[7])};
  uint4 o1 = {pk(a[8], a[9]), pk(a[10], a[11]), pk(a[12], a[13]), pk(a[14], a[15])};
  unsigned short* yp = y1g + (size_t)half * N * 16 + (size_t)node * 16;
  *(uint4*)(yp) = o0;
  *(uint4*)(yp + 8) = o1;
}

// layer 2, ONE 16-feat plane: LDS CSR rebuild + register aggregation +
// fused sorted-batch graph pooling -> atomicAdd P[G][32] at pofs
__global__ __launch_bounds__(512) void k_fuse2(const unsigned short* __restrict__ y1p,
                                               const int* __restrict__ staging,
                                               const int* __restrict__ bucket_off,
                                               const float* __restrict__ dinv,
                                               const int* __restrict__ batch, int N,
                                               int pofs, float* __restrict__ P) {
  __shared__ int list[CAP];
  __shared__ int cnt[BKTN], sc[BKTN], lcur[BKTN];
  __shared__ float pool[8 * 16];
  int tid = threadIdx.x, b = blockIdx.x;
  int nloc = tid >> 1, half = tid & 1;
  int node = (b << BSH) + nloc;
  float acc[8];
  if (node < N) {
    uint4 v = *(const uint4*)(y1p + (size_t)node * 16 + half * 8);
    acc[0] = bf2f(v.x & 0xFFFF); acc[1] = bf2f(v.x >> 16);
    acc[2] = bf2f(v.y & 0xFFFF); acc[3] = bf2f(v.y >> 16);
    acc[4] = bf2f(v.z & 0xFFFF); acc[5] = bf2f(v.z >> 16);
    acc[6] = bf2f(v.w & 0xFFFF); acc[7] = bf2f(v.w >> 16);
  } else {
#pragma unroll
    for (int k = 0; k < 8; ++k) acc[k] = 0.f;
  }
  int beg = bucket_off[b], end = bucket_off[b + 1];
  for (int cbeg = beg; cbeg < end; cbeg += CAP) {
    int cend = min(end, cbeg + CAP);
    if (tid < BKTN) cnt[tid] = 0;
    __syncthreads();
    for (int i = cbeg + tid; i < cend; i += 512)
      atomicAdd(&cnt[staging[i] & (BKTN - 1)], 1);
    __syncthreads();
    if (tid < BKTN) sc[tid] = cnt[tid];
    __syncthreads();
    for (int o = 1; o < BKTN; o <<= 1) {
      int u = (tid < BKTN && tid >= o) ? sc[tid - o] : 0;
      __syncthreads();
      if (tid < BKTN) sc[tid] += u;
      __syncthreads();
    }
    if (tid < BKTN) {
      int st = sc[tid] - cnt[tid];
      sc[tid] = st;
      lcur[tid] = st;
    }
    __syncthreads();
    for (int i = cbeg + tid; i < cend; i += 512) {
      int p = staging[i];
      int pos = atomicAdd(&lcur[p & (BKTN - 1)], 1);
      list[pos] = p >> BSH;
    }
    __syncthreads();
    if (node < N) gather8(y1p + half * 8, list, sc[nloc], cnt[nloc], acc);
    __syncthreads();
  }
  int myg = -1;
  if (node < N) {
    float d = dinv[node];
#pragma unroll
    for (int k = 0; k < 8; ++k) acc[k] *= d;
    myg = batch[node];
  }
  int g0 = batch[b << BSH];
  int g1 = batch[min((b << BSH) + BKTN - 1, N - 1)];
  for (int clo = g0; clo <= g1; clo += 8) {
    for (int j = tid; j < 8 * 16; j += 512) pool[j] = 0.f;
    __syncthreads();
    if (myg >= clo && myg < clo + 8) {
      float* pp = pool + (myg - clo) * 16 + half * 8;
#pragma unroll
      for (int k = 0; k < 8; ++k) atomicAdd(pp + k, acc[k]);
    }
    __syncthreads();
    int ng = min(8, g1 - clo + 1);
    for (int j = tid; j < ng * 16; j += 512)
      atomicAdd(&P[(size_t)(clo + (j >> 4)) * 32 + pofs + (j & 15)], pool[j]);
    __syncthreads();
  }
}

// out[g] = P[g] @ W2 + cnt[g]*b2; cnt via binary search on sorted batch
__global__ __launch_bounds__(64) void k_final(const float* __restrict__ P,
                                              const int* __restrict__ batch, int N,
                                              const float* __restrict__ W2,
                                              const float* __restrict__ b2,
                                              float* __restrict__ out) {
  __shared__ float pr[32];
  __shared__ int se[2];
  int g = blockIdx.x, tid = threadIdx.x;
  if (tid < 2) {
    int v = g + tid;
    int lo = 0, hi = N;
    while (lo < hi) {
      int mid = (lo + hi) >> 1;
      if (batch[mid] < v) lo = mid + 1; else hi = mid;
    }
    se[tid] = lo;
  }
  if (tid < 32) pr[tid] = P[(size_t)g * 32 + tid];
  __syncthreads();
  if (tid < 41) {
    float o = (float)(se[1] - se[0]) * b2[tid];
#pragma unroll
    for (int k = 0; k < 32; ++k) o += pr[k] * W2[k * 41 + tid];
    out[(size_t)g * 41 + tid] = o;
  }
}

extern "C" void kernel_launch(void* const* d_in, const int* in_sizes, int n_in,
                              void* d_out, int out_size, void* d_ws, size_t ws_size,
                              hipStream_t stream) {
  const int* x_ids = (const int*)d_in[0];
  const int* edge_index = (const int*)d_in[1];
  const int* batch = (const int*)d_in[2];
  const float* emb = (const float*)d_in[3];
  const float* W1 = (const float*)d_in[4];
  const float* b1 = (const float*)d_in[5];
  const float* W2 = (const float*)d_in[6];
  const float* b2 = (const float*)d_in[7];
  float* out = (float*)d_out;

  const int N = in_sizes[0];
  const int E = in_sizes[1] / 2;
  const int G = out_size / 41;
  const int* row = edge_index;
  const int* col = edge_index + E;

  const int nbkt = (N + BKTN - 1) >> BSH;       // 391 fine buckets
  int nblk = (E + EPB - 1) / EPB;               // 196
  const int nblkp = (nblk + 7) & ~7;            // 200 (pad for XCD swizzle)
  const int tot = nbkt * nblkp;                 // ~78K
  const int nscan = (tot + 1023) >> 10;         // ~77

  char* ws = (char*)d_ws;
  size_t woff = 0;
  auto alloc = [&](size_t bytes) -> char* {
    char* p = ws + woff;
    woff += (bytes + 255) & ~(size_t)255;
    return p;
  };
  int* staging = (int*)alloc((size_t)E * 4);
  float* dinv = (float*)alloc((size_t)N * 4);
  unsigned short* ag1 = (unsigned short*)alloc((size_t)N * 16 * 2);
  unsigned short* y1g = (unsigned short*)alloc((size_t)N * 32 * 2);
  int* hist = (int*)alloc((size_t)tot * 4);
  int* off = (int*)alloc((size_t)tot * 4);
  int* bucket_off = (int*)alloc(((size_t)nbkt + 1) * 4);
  int* bsums = (int*)alloc((size_t)nscan * 4);
  float* P = (float*)alloc((size_t)G * 32 * 4);
  (void)ws_size; (void)n_in;

  hipMemsetAsync(P, 0, (size_t)G * 32 * 4, stream);

  k_hist<<<nblkp, 1024, 0, stream>>>(col, E, nbkt, nblkp, hist);
  k_scan_a<<<nscan, 1024, 0, stream>>>(hist, tot, off, bsums);
  k_scan_c<<<nscan, 1024, 0, stream>>>(tot, nblkp, nbkt, E, nscan, bsums, off, bucket_off);
  k_scatter<<<nblkp, 1024, 0, stream>>>(row, col, E, nbkt, nblkp, off, staging);
  k_degprep<<<nbkt, BKTN, 0, stream>>>(staging, bucket_off, x_ids, emb, N, dinv, ag1);
  k_fuse1<<<nbkt, 512, 0, stream>>>(ag1, staging, bucket_off, dinv, W1, b1, N, y1g);
  k_fuse2<<<nbkt, 512, 0, stream>>>(y1g, staging, bucket_off, dinv, batch, N, 0, P);
  k_fuse2<<<nbkt, 512, 0, stream>>>(y1g + (size_t)N * 16, staging, bucket_off, dinv,
                                    batch, N, 16, P);
  k_final<<<G, 64, 0, stream>>>(P, batch, N, W2, b2, out);
}

// Round 13
// 226.475 us; speedup vs baseline: 1.0573x; 1.0573x over previous
//
#include <hip/hip_runtime.h>

// 2-layer GCN: counting sort to fine buckets + ONE global node-sorted edge
// list (built once, coalesced flush) + register aggregation, bf16 planes:
//   k_hist/k_scan: per-(fine bucket, scatter block) segment offsets
//   k_scatter: 200 blocks x 1024 thr, EPB=16384; in-LDS bucket sort +
//              coalesced segment flush (R12)
//   k_build:   per fine bucket: LDS count -> col_ptr/dinv + fused emb
//              transform (ag1=bf16(emb*dinv)); LDS fill sorted-by-node ->
//              COALESCED flush to edge_row (R5's direct global fill had 4x
//              amp; this has none)
//   k_fuse1:   coalesced copy of edge_row window -> LDS (NO rebuild: R12
//              showed fuse kernels not chain-bound; the 3x redundant CSR
//              rebuild was the remaining fat); register gather; fused
//              16->32 GEMV+ReLU -> y1g (2 planes)
//   k_fuse2 x2 (ONE PLANE each -- R8: merged planes blew the 4MB L2):
//              same copy + gather + fused sorted-batch pooling -> P
//   k_final:   out[g] = P[g]@W2 + cnt[g]*b2
//
// Standing lessons: R1/R2 no scattered-4B global stores / no hot global
// atomics; R4 no single-block stages; R6 register accumulation only; R3/R8
// one bf16 plane (3.2MB) per gather pass; R10 no cooperative launch.

constexpr int EPB = 16384;         // edges per hist/scatter block
constexpr int BSH = 8;             // 256 nodes per fine bucket
constexpr int BKTN = 1 << BSH;
constexpr int CAP = 10240;         // LDS edge-list capacity (chunked if over)

__device__ inline unsigned short f2bf(float x) {
  unsigned u = __float_as_uint(x);
  u += 0x7FFF + ((u >> 16) & 1);   // round-to-nearest-even
  return (unsigned short)(u >> 16);
}
__device__ inline float bf2f(unsigned short h) {
  return __uint_as_float((unsigned)h << 16);
}
__device__ inline unsigned pk(float a, float b) {
  return (unsigned)f2bf(a) | ((unsigned)f2bf(b) << 16);
}
__device__ __forceinline__ void add8(float acc[8], uint4 v) {
  acc[0] += bf2f(v.x & 0xFFFF); acc[1] += bf2f(v.x >> 16);
  acc[2] += bf2f(v.y & 0xFFFF); acc[3] += bf2f(v.y >> 16);
  acc[4] += bf2f(v.z & 0xFFFF); acc[5] += bf2f(v.z >> 16);
  acc[6] += bf2f(v.w & 0xFFFF); acc[7] += bf2f(v.w >> 16);
}

// 4-wide unrolled neighbor gather over LDS list window
__device__ __forceinline__ void gather8(const unsigned short* __restrict__ base,
                                        const int* list, int st, int dg,
                                        float acc[8]) {
  int j = 0;
  for (; j + 4 <= dg; j += 4) {
    int r0 = list[st + j], r1 = list[st + j + 1];
    int r2 = list[st + j + 2], r3 = list[st + j + 3];
    uint4 v0 = *(const uint4*)(base + (size_t)r0 * 16);
    uint4 v1 = *(const uint4*)(base + (size_t)r1 * 16);
    uint4 v2 = *(const uint4*)(base + (size_t)r2 * 16);
    uint4 v3 = *(const uint4*)(base + (size_t)r3 * 16);
    add8(acc, v0); add8(acc, v1); add8(acc, v2); add8(acc, v3);
  }
  for (; j < dg; ++j)
    add8(acc, *(const uint4*)(base + (size_t)list[st + j] * 16));
}

// XCD swizzle: adjacent hist columns handled by same-XCD blocks (blk%8 heur.)
__device__ __forceinline__ int swz(int b, int nblkp) {
  return (b & 7) * (nblkp >> 3) + (b >> 3);
}

// per-block LDS histogram of fine col buckets
__global__ __launch_bounds__(1024) void k_hist(const int* __restrict__ col, int E,
                                               int nbkt, int nblkp,
                                               int* __restrict__ hist) {
  __shared__ int h[512];
  int tid = threadIdx.x;
  int blk = swz(blockIdx.x, nblkp);
  for (int i = tid; i < nbkt; i += 1024) h[i] = 0;
  __syncthreads();
  int e0 = blk * EPB, e1 = min(E, e0 + EPB);
  for (int e = e0 + tid; e < e1; e += 1024) atomicAdd(&h[col[e] >> BSH], 1);
  __syncthreads();
  for (int b = tid; b < nbkt; b += 1024) hist[b * nblkp + blk] = h[b];
}

// multi-block scan, stage 1: block-local exclusive scan + block sums
__global__ __launch_bounds__(1024) void k_scan_a(const int* __restrict__ hist, int tot,
                                                 int* __restrict__ off,
                                                 int* __restrict__ bsums) {
  __shared__ int sd[1024];
  int tid = threadIdx.x;
  int i = blockIdx.x * 1024 + tid;
  int v = (i < tot) ? hist[i] : 0;
  sd[tid] = v;
  __syncthreads();
  for (int o = 1; o < 1024; o <<= 1) {
    int u = (tid >= o) ? sd[tid - o] : 0;
    __syncthreads();
    sd[tid] += u;
    __syncthreads();
  }
  if (i < tot) off[i] = sd[tid] - v;  // block-local exclusive
  if (tid == 1023) bsums[blockIdx.x] = sd[tid];
}

// stage 2: add prefix of block sums (tree-reduced); derive bucket starts
__global__ __launch_bounds__(1024) void k_scan_c(int tot, int nblkp, int nbkt, int E,
                                                 int nscan,
                                                 const int* __restrict__ bsums,
                                                 int* __restrict__ off,
                                                 int* __restrict__ bucket_off) {
  __shared__ int sd[1024];
  int tid = threadIdx.x, b = blockIdx.x;
  sd[tid] = (tid < b && tid < nscan) ? bsums[tid] : 0;
  __syncthreads();
  for (int o = 512; o >= 1; o >>= 1) {
    if (tid < o) sd[tid] += sd[tid + o];
    __syncthreads();
  }
  int sbase = sd[0];
  int i = b * 1024 + tid;
  if (i < tot) {
    int v = off[i] + sbase;
    off[i] = v;
    if (i % nblkp == 0) bucket_off[i / nblkp] = v;
  }
  if (i == 0) bucket_off[nbkt] = E;
}

// scatter: in-LDS counting sort of this block's 16K edges, then flush each
// bucket segment with contiguous lane-consecutive stores
__global__ __launch_bounds__(1024) void k_scatter(const int* __restrict__ row,
                                                  const int* __restrict__ col, int E,
                                                  int nbkt, int nblkp,
                                                  const int* __restrict__ off,
                                                  int* __restrict__ staging) {
  __shared__ int sbuf[EPB];
  __shared__ int cnt[512], sc[512], cur[512];
  int tid = threadIdx.x;
  int lane = tid & 63, wv = tid >> 6;
  int blk = swz(blockIdx.x, nblkp);
  if (tid < 512) cnt[tid] = 0;
  __syncthreads();
  int e0 = blk * EPB, e1 = min(E, e0 + EPB);
  for (int e = e0 + tid; e < e1; e += 1024)
    atomicAdd(&cnt[col[e] >> BSH], 1);
  __syncthreads();
  if (tid < 512) sc[tid] = cnt[tid];
  __syncthreads();
  for (int o = 1; o < 512; o <<= 1) {
    int u = (tid < 512 && tid >= o) ? sc[tid - o] : 0;
    __syncthreads();
    if (tid < 512) sc[tid] += u;
    __syncthreads();
  }
  if (tid < 512) { int st = sc[tid] - cnt[tid]; sc[tid] = st; cur[tid] = st; }
  __syncthreads();
  for (int e = e0 + tid; e < e1; e += 1024) {
    int c = col[e];
    int b = c >> BSH;
    int pos = atomicAdd(&cur[b], 1);
    sbuf[pos] = (row[e] << BSH) | (c & (BKTN - 1));
  }
  __syncthreads();
  for (int b = wv; b < nbkt; b += 16) {
    int lbeg = sc[b], lcnt = cnt[b];
    int g = off[b * nblkp + blk];
    for (int j = lane; j < lcnt; j += 64)
      staging[g + j] = sbuf[lbeg + j];
  }
}

// per fine bucket: LDS count -> col_ptr/dinv + fused emb transform; LDS fill
// sorted-by-node; COALESCED flush to edge_row
__global__ __launch_bounds__(512) void k_build(const int* __restrict__ staging,
                                               const int* __restrict__ bucket_off,
                                               const int* __restrict__ x_ids,
                                               const float* __restrict__ emb,
                                               int N, int E,
                                               int* __restrict__ col_ptr,
                                               float* __restrict__ dinv,
                                               unsigned short* __restrict__ ag1,
                                               int* __restrict__ edge_row) {
  __shared__ int list[CAP];
  __shared__ int cnt[BKTN], sc[BKTN], lcur[BKTN];
  int tid = threadIdx.x, b = blockIdx.x;
  int beg = bucket_off[b], end = bucket_off[b + 1];
  if (tid < BKTN) cnt[tid] = 0;
  __syncthreads();
  for (int i = beg + tid; i < end; i += 512)
    atomicAdd(&cnt[staging[i] & (BKTN - 1)], 1);
  __syncthreads();
  if (tid < BKTN) sc[tid] = cnt[tid];
  __syncthreads();
  for (int o = 1; o < BKTN; o <<= 1) {
    int u = (tid < BKTN && tid >= o) ? sc[tid - o] : 0;
    __syncthreads();
    if (tid < BKTN) sc[tid] += u;
    __syncthreads();
  }
  if (tid < BKTN) {
    int excl = sc[tid] - cnt[tid];
    sc[tid] = excl;
    lcur[tid] = excl;
    int node = (b << BSH) + tid;
    if (node < N) col_ptr[node] = beg + excl;
  }
  if (b == 0 && tid == 0) col_ptr[N] = E;
  __syncthreads();
  bool fits = (end - beg) <= CAP;
  if (fits) {
    for (int i = beg + tid; i < end; i += 512) {
      int p = staging[i];
      list[atomicAdd(&lcur[p & (BKTN - 1)], 1)] = p >> BSH;
    }
    __syncthreads();
    for (int i = beg + tid; i < end; i += 512)
      edge_row[i] = list[i - beg];
  } else {  // never hit at this scale; correct fallback
    for (int i = beg + tid; i < end; i += 512) {
      int p = staging[i];
      edge_row[beg + atomicAdd(&lcur[p & (BKTN - 1)], 1)] = p >> BSH;
    }
  }
  // fused embedding transform (cnt intact): 2 lanes/node x 8 feats
  int nloc = tid >> 1, half = tid & 1;
  int node = (b << BSH) + nloc;
  if (node < N) {
    float d = rsqrtf((float)(cnt[nloc] + 1));  // +1 self-loop
    if (half == 0) dinv[node] = d;
    const float* er = emb + (size_t)x_ids[node] * 16 + half * 8;
    float4 e0 = *(const float4*)(er);
    float4 e1 = *(const float4*)(er + 4);
    uint4 o;
    o.x = pk(e0.x * d, e0.y * d); o.y = pk(e0.z * d, e0.w * d);
    o.z = pk(e1.x * d, e1.y * d); o.w = pk(e1.z * d, e1.w * d);
    *(uint4*)(ag1 + (size_t)node * 16 + half * 8) = o;
  }
}

// layer 1: coalesced edge_row window copy -> LDS; register gather; fused
// 16->32 GEMV/ReLU. 512 threads: 2 lanes/node (half = 8 features).
__global__ __launch_bounds__(512) void k_fuse1(const unsigned short* __restrict__ ag1,
                                               const int* __restrict__ edge_row,
                                               const int* __restrict__ col_ptr,
                                               const float* __restrict__ dinv,
                                               const float* __restrict__ W1,
                                               const float* __restrict__ b1, int N,
                                               unsigned short* __restrict__ y1g) {
  __shared__ int list[CAP];
  __shared__ float W[512];
  __shared__ float bb[32];
  int tid = threadIdx.x, b = blockIdx.x;
  W[tid] = W1[tid];
  if (tid < 32) bb[tid] = b1[tid];
  int nloc = tid >> 1, half = tid & 1;
  int node = (b << BSH) + nloc;
  bool valid = node < N;
  int beg = col_ptr[b << BSH];
  int end = col_ptr[min((b + 1) << BSH, N)];
  int ms = 0, me = 0;
  float acc[8];
  if (valid) {
    ms = col_ptr[node];
    me = col_ptr[node + 1];
    uint4 v = *(const uint4*)(ag1 + (size_t)node * 16 + half * 8);
    acc[0] = bf2f(v.x & 0xFFFF); acc[1] = bf2f(v.x >> 16);
    acc[2] = bf2f(v.y & 0xFFFF); acc[3] = bf2f(v.y >> 16);
    acc[4] = bf2f(v.z & 0xFFFF); acc[5] = bf2f(v.z >> 16);
    acc[6] = bf2f(v.w & 0xFFFF); acc[7] = bf2f(v.w >> 16);
  } else {
#pragma unroll
    for (int k = 0; k < 8; ++k) acc[k] = 0.f;
  }
  for (int cbeg = beg; cbeg < end; cbeg += CAP) {
    int cend = min(end, cbeg + CAP);
    __syncthreads();
    for (int i = cbeg + tid; i < cend; i += 512) list[i - cbeg] = edge_row[i];
    __syncthreads();
    if (valid) {
      int st = max(ms, cbeg), en = min(me, cend);
      if (en > st) gather8(ag1 + half * 8, list, st - cbeg, en - st, acc);
    }
  }
  if (!valid) return;
  float d = dinv[node];
  float sx[8], xo[8];
#pragma unroll
  for (int k = 0; k < 8; ++k) sx[k] = acc[k] * d;
#pragma unroll
  for (int k = 0; k < 8; ++k) xo[k] = __shfl_xor(sx[k], 1);
  float x[16];
  if (half == 0) {
#pragma unroll
    for (int k = 0; k < 8; ++k) { x[k] = sx[k]; x[8 + k] = xo[k]; }
  } else {
#pragma unroll
    for (int k = 0; k < 8; ++k) { x[k] = xo[k]; x[8 + k] = sx[k]; }
  }
  int j0 = half * 16;
  float a[16];
#pragma unroll
  for (int j = 0; j < 16; ++j) a[j] = bb[j0 + j];
#pragma unroll
  for (int k = 0; k < 16; ++k) {
    float xv = x[k];
#pragma unroll
    for (int j = 0; j < 16; ++j) a[j] += xv * W[k * 32 + j0 + j];
  }
#pragma unroll
  for (int j = 0; j < 16; ++j) a[j] = fmaxf(a[j], 0.f) * d;
  uint4 o0 = {pk(a[0], a[1]), pk(a[2], a[3]), pk(a[4], a[5]), pk(a[6], a[7])};
  uint4 o1 = {pk(a[8], a[9]), pk(a[10], a[11]), pk(a[12], a[13]), pk(a[14], a[15])};
  unsigned short* yp = y1g + (size_t)half * N * 16 + (size_t)node * 16;
  *(uint4*)(yp) = o0;
  *(uint4*)(yp + 8) = o1;
}

// layer 2, ONE 16-feat plane: coalesced window copy + register gather +
// fused sorted-batch graph pooling -> atomicAdd P[G][32] at pofs
__global__ __launch_bounds__(512) void k_fuse2(const unsigned short* __restrict__ y1p,
                                               const int* __restrict__ edge_row,
                                               const int* __restrict__ col_ptr,
                                               const float* __restrict__ dinv,
                                               const int* __restrict__ batch, int N,
                                               int pofs, float* __restrict__ P) {
  __shared__ int list[CAP];
  __shared__ float pool[8 * 16];
  int tid = threadIdx.x, b = blockIdx.x;
  int nloc = tid >> 1, half = tid & 1;
  int node = (b << BSH) + nloc;
  bool valid = node < N;
  int beg = col_ptr[b << BSH];
  int end = col_ptr[min((b + 1) << BSH, N)];
  int ms = 0, me = 0;
  float acc[8];
  if (valid) {
    ms = col_ptr[node];
    me = col_ptr[node + 1];
    uint4 v = *(const uint4*)(y1p + (size_t)node * 16 + half * 8);
    acc[0] = bf2f(v.x & 0xFFFF); acc[1] = bf2f(v.x >> 16);
    acc[2] = bf2f(v.y & 0xFFFF); acc[3] = bf2f(v.y >> 16);
    acc[4] = bf2f(v.z & 0xFFFF); acc[5] = bf2f(v.z >> 16);
    acc[6] = bf2f(v.w & 0xFFFF); acc[7] = bf2f(v.w >> 16);
  } else {
#pragma unroll
    for (int k = 0; k < 8; ++k) acc[k] = 0.f;
  }
  for (int cbeg = beg; cbeg < end; cbeg += CAP) {
    int cend = min(end, cbeg + CAP);
    __syncthreads();
    for (int i = cbeg + tid; i < cend; i += 512) list[i - cbeg] = edge_row[i];
    __syncthreads();
    if (valid) {
      int st = max(ms, cbeg), en = min(me, cend);
      if (en > st) gather8(y1p + half * 8, list, st - cbeg, en - st, acc);
    }
  }
  int myg = -1;
  if (valid) {
    float d = dinv[node];
#pragma unroll
    for (int k = 0; k < 8; ++k) acc[k] *= d;
    myg = batch[node];
  }
  int g0 = batch[b << BSH];
  int g1 = batch[min((b << BSH) + BKTN - 1, N - 1)];
  for (int clo = g0; clo <= g1; clo += 8) {
    for (int j = tid; j < 8 * 16; j += 512) pool[j] = 0.f;
    __syncthreads();
    if (myg >= clo && myg < clo + 8) {
      float* pp = pool + (myg - clo) * 16 + half * 8;
#pragma unroll
      for (int k = 0; k < 8; ++k) atomicAdd(pp + k, acc[k]);
    }
    __syncthreads();
    int ng = min(8, g1 - clo + 1);
    for (int j = tid; j < ng * 16; j += 512)
      atomicAdd(&P[(size_t)(clo + (j >> 4)) * 32 + pofs + (j & 15)], pool[j]);
    __syncthreads();
  }
}

// out[g] = P[g] @ W2 + cnt[g]*b2; cnt via binary search on sorted batch
__global__ __launch_bounds__(64) void k_final(const float* __restrict__ P,
                                              const int* __restrict__ batch, int N,
                                              const float* __restrict__ W2,
                                              const float* __restrict__ b2,
                                              float* __restrict__ out) {
  __shared__ float pr[32];
  __shared__ int se[2];
  int g = blockIdx.x, tid = threadIdx.x;
  if (tid < 2) {
    int v = g + tid;
    int lo = 0, hi = N;
    while (lo < hi) {
      int mid = (lo + hi) >> 1;
      if (batch[mid] < v) lo = mid + 1; else hi = mid;
    }
    se[tid] = lo;
  }
  if (tid < 32) pr[tid] = P[(size_t)g * 32 + tid];
  __syncthreads();
  if (tid < 41) {
    float o = (float)(se[1] - se[0]) * b2[tid];
#pragma unroll
    for (int k = 0; k < 32; ++k) o += pr[k] * W2[k * 41 + tid];
    out[(size_t)g * 41 + tid] = o;
  }
}

extern "C" void kernel_launch(void* const* d_in, const int* in_sizes, int n_in,
                              void* d_out, int out_size, void* d_ws, size_t ws_size,
                              hipStream_t stream) {
  const int* x_ids = (const int*)d_in[0];
  const int* edge_index = (const int*)d_in[1];
  const int* batch = (const int*)d_in[2];
  const float* emb = (const float*)d_in[3];
  const float* W1 = (const float*)d_in[4];
  const float* b1 = (const float*)d_in[5];
  const float* W2 = (const float*)d_in[6];
  const float* b2 = (const float*)d_in[7];
  float* out = (float*)d_out;

  const int N = in_sizes[0];
  const int E = in_sizes[1] / 2;
  const int G = out_size / 41;
  const int* row = edge_index;
  const int* col = edge_index + E;

  const int nbkt = (N + BKTN - 1) >> BSH;       // 391 fine buckets
  int nblk = (E + EPB - 1) / EPB;               // 196
  const int nblkp = (nblk + 7) & ~7;            // 200 (pad for XCD swizzle)
  const int tot = nbkt * nblkp;                 // ~78K
  const int nscan = (tot + 1023) >> 10;         // ~77

  char* ws = (char*)d_ws;
  size_t woff = 0;
  auto alloc = [&](size_t bytes) -> char* {
    char* p = ws + woff;
    woff += (bytes + 255) & ~(size_t)255;
    return p;
  };
  int* staging = (int*)alloc((size_t)E * 4);
  int* edge_row = (int*)alloc((size_t)E * 4);
  int* col_ptr = (int*)alloc(((size_t)N + 1) * 4);
  float* dinv = (float*)alloc((size_t)N * 4);
  unsigned short* ag1 = (unsigned short*)alloc((size_t)N * 16 * 2);
  unsigned short* y1g = (unsigned short*)alloc((size_t)N * 32 * 2);
  int* hist = (int*)alloc((size_t)tot * 4);
  int* off = (int*)alloc((size_t)tot * 4);
  int* bucket_off = (int*)alloc(((size_t)nbkt + 1) * 4);
  int* bsums = (int*)alloc((size_t)nscan * 4);
  float* P = (float*)alloc((size_t)G * 32 * 4);
  (void)ws_size; (void)n_in;

  hipMemsetAsync(P, 0, (size_t)G * 32 * 4, stream);

  k_hist<<<nblkp, 1024, 0, stream>>>(col, E, nbkt, nblkp, hist);
  k_scan_a<<<nscan, 1024, 0, stream>>>(hist, tot, off, bsums);
  k_scan_c<<<nscan, 1024, 0, stream>>>(tot, nblkp, nbkt, E, nscan, bsums, off, bucket_off);
  k_scatter<<<nblkp, 1024, 0, stream>>>(row, col, E, nbkt, nblkp, off, staging);
  k_build<<<nbkt, 512, 0, stream>>>(staging, bucket_off, x_ids, emb, N, E,
                                    col_ptr, dinv, ag1, edge_row);
  k_fuse1<<<nbkt, 512, 0, stream>>>(ag1, edge_row, col_ptr, dinv, W1, b1, N, y1g);
  k_fuse2<<<nbkt, 512, 0, stream>>>(y1g, edge_row, col_ptr, dinv, batch, N, 0, P);
  k_fuse2<<<nbkt, 512, 0, stream>>>(y1g + (size_t)N * 16, edge_row, col_ptr, dinv,
                                    batch, N, 16, P);
  k_final<<<G, 64, 0, stream>>>(P, batch, N, W2, b2, out);
}